// Round 16
// baseline (88.642 us; speedup 1.0000x reference)
//
#include <hip/hip_runtime.h>
#include <math.h>

// DynamicRouting: C=1024, K=64, H=512.
// Round-16: kill the barrier-drain serialization. HIP __syncthreads emits
// s_waitcnt vmcnt(0) -> every per-hs barrier in r12/r15 drained the whole
// prefetch queue => ~10 serial L3 round-trips per block (r12==r15==81us
// despite different pipelining: the invariant was the barrier count).
// Fix: stage the ENTIRE capsule (64KB fp16, single buffer) in one 16-load
// burst, ONE barrier, then 8 barrier-free MFMA phases (slab read-only,
// bf reg-dbuf survives since nothing drains it). Routing = r15 verified
// deferred-alpha (3 barriers). Staging swizzle + Wp B-frag order = r12
// verified; acc layout: acc[i*4+j][r]=xh[k][g], k=i*16+(lane>>4)*4+r,
// g=wave*64+j*16+(lane&15).

#define KC 64
#define HD 512
#define NT 512

typedef _Float16 half8  __attribute__((ext_vector_type(8)));
typedef _Float16 half4v __attribute__((ext_vector_type(4)));
typedef float    f32x4  __attribute__((ext_vector_type(4)));

// ---- W (fp32 [g][h]) -> fp16 in B-fragment order (verified r12) ----
__launch_bounds__(256)
__global__ void cast_w_kernel(const float* __restrict__ W, _Float16* __restrict__ Wp) {
    int u    = blockIdx.x * 256 + threadIdx.x;    // 0..32767
    int lane = u & 63;
    int j    = (u >> 6) & 3;
    int ks   = (u >> 8) & 1;
    int hs   = (u >> 9) & 7;
    int wv   = (u >> 12) & 7;
    int g  = wv * 64 + j * 16 + (lane & 15);
    int h0 = hs * 64 + ks * 32 + (lane >> 4) * 8;
    const float4* src = reinterpret_cast<const float4*>(W + (size_t)g * HD + h0);
    float4 a = src[0], b = src[1];
    half8 h = { (_Float16)a.x, (_Float16)a.y, (_Float16)a.z, (_Float16)a.w,
                (_Float16)b.x, (_Float16)b.y, (_Float16)b.z, (_Float16)b.w };
    *reinterpret_cast<half8*>(Wp + (size_t)u * 8) = h;
}

// ---- fused proj + routing, one capsule per block ----
__launch_bounds__(NT, 2)
__global__ void routing_kernel(const float* __restrict__ enc,
                               const _Float16* __restrict__ Wp,
                               float* __restrict__ out) {
    __shared__ _Float16 slab[8][8][64][8];      // 64 KB single buffer [hs][plane][row][e]
    __shared__ float chatL[HD];                 // 2 KB
    __shared__ float bpart[2][8][KC];           // 4 KB raw-dot partials (dbuf)
    __shared__ float redp[2][8];                // ||chat||^2 partials (dbuf)

    const int tid  = threadIdx.x;
    const int lane = tid & 63;
    const int wave = tid >> 6;
    const int l15  = lane & 15, l4 = lane >> 4;
    const int c    = blockIdx.x;
    const float* ebase = enc + (size_t)c * (KC * HD);
    const _Float16* wbase = Wp + ((size_t)wave << 15) + (lane << 3);

    // staging geometry (verified r12)
    const int r0   = tid >> 4;                  // 0..31
    const int c40  = (tid & 15) << 2;           // 0..60
    const int ks_w = c40 >> 5;
    const int l4g  = (c40 >> 3) & 3;
    const int e0w  = c40 & 7;                   // 0 or 4
    const int prow = (l4g * 16 + (r0 & 15)) ^ (l4g << 1);
    const int p0   = (r0 >> 4) * 2 + ks_w;
    const int p1   = p0 + 4;
    const int plane_r = lane ^ ((lane >> 4) << 1);

    half8 bf[2][8];                             // W frags dbuf (static idx)
    auto bload = [&](int hs) {
        #pragma unroll
        for (int q = 0; q < 8; ++q)
            bf[hs & 1][q] = *reinterpret_cast<const half8*>(wbase + hs * 4096 + q * 512);
    };

    // ---- stage whole capsule: 16-load burst, deep memory pipeline ----
    float4 ev[8][2];
    #pragma unroll
    for (int hs = 0; hs < 8; ++hs) {
        ev[hs][0] = *reinterpret_cast<const float4*>(ebase + (size_t)r0 * HD + hs * 64 + c40);
        ev[hs][1] = *reinterpret_cast<const float4*>(ebase + (size_t)(r0 + 32) * HD + hs * 64 + c40);
    }
    bload(0);
    #pragma unroll
    for (int hs = 0; hs < 8; ++hs) {
        float4 v0 = ev[hs][0], v1 = ev[hs][1];
        half4v h0 = { (_Float16)v0.x, (_Float16)v0.y, (_Float16)v0.z, (_Float16)v0.w };
        half4v h1 = { (_Float16)v1.x, (_Float16)v1.y, (_Float16)v1.z, (_Float16)v1.w };
        *reinterpret_cast<half4v*>(&slab[hs][p0][prow][e0w]) = h0;
        *reinterpret_cast<half4v*>(&slab[hs][p1][prow][e0w]) = h1;
    }

    f32x4 acc[16];
    #pragma unroll
    for (int i = 0; i < 16; ++i) acc[i] = (f32x4){0.f, 0.f, 0.f, 0.f};

    __syncthreads();                            // the ONLY projection barrier

    // ---- projection: 8 barrier-free phases ----
    #pragma unroll
    for (int hs = 0; hs < 8; ++hs) {
        if (hs < 7) bload(hs + 1);              // reg-dbuf prefetch (survives: no barrier)
        #pragma unroll
        for (int ks = 0; ks < 2; ++ks) {
            half8 af[4];
            #pragma unroll
            for (int i = 0; i < 4; ++i)
                af[i] = *reinterpret_cast<const half8*>(&slab[hs][i * 2 + ks][plane_r][0]);
            #pragma unroll
            for (int i = 0; i < 4; ++i)
                #pragma unroll
                for (int j = 0; j < 4; ++j)
                    acc[i * 4 + j] = __builtin_amdgcn_mfma_f32_16x16x32_f16(
                        af[i], bf[hs & 1][ks * 4 + j], acc[i * 4 + j], 0, 0, 0);
        }
    }

    // ---- routing: deferred-alpha, 1 barrier per iteration (verified r15) ----
    float breg = 0.0f;                          // b[k=lane], redundant per wave
    float chv[4];

    // iter 0: dk = 1/64
    {
        #pragma unroll
        for (int j = 0; j < 4; ++j) chv[j] = 0.f;
        #pragma unroll
        for (int i = 0; i < 4; ++i)
            #pragma unroll
            for (int r = 0; r < 4; ++r) {
                #pragma unroll
                for (int j = 0; j < 4; ++j)
                    chv[j] += (1.0f / 64.0f) * acc[i * 4 + j][r];
            }
        #pragma unroll
        for (int j = 0; j < 4; ++j) {
            chv[j] += __shfl_xor(chv[j], 16);
            chv[j] += __shfl_xor(chv[j], 32);
        }
        float p = chv[0] * chv[0] + chv[1] * chv[1] + chv[2] * chv[2] + chv[3] * chv[3];
        #pragma unroll
        for (int off = 1; off <= 8; off <<= 1) p += __shfl_xor(p, off);
        if (lane == 0) redp[0][wave] = p;
        #pragma unroll
        for (int i = 0; i < 4; ++i)
            #pragma unroll
            for (int r = 0; r < 4; ++r) {
                float s = acc[i * 4 + 0][r] * chv[0] + acc[i * 4 + 1][r] * chv[1]
                        + acc[i * 4 + 2][r] * chv[2] + acc[i * 4 + 3][r] * chv[3];
                #pragma unroll
                for (int off = 1; off <= 8; off <<= 1) s += __shfl_xor(s, off);
                if (l15 == 0) bpart[0][wave][i * 16 + l4 * 4 + r] = s;
            }
        __syncthreads();
    }

    // iters 1,2
    #pragma unroll
    for (int it = 1; it < 3; ++it) {
        const int rp = (it - 1) & 1, wp = it & 1;
        float n2 = 0.f;
        #pragma unroll
        for (int w = 0; w < 8; ++w) n2 += redp[rp][w];
        float alpha = sqrtf(n2) / (1.0f + n2);
        float dot = 0.f;
        #pragma unroll
        for (int w = 0; w < 8; ++w) dot += bpart[rp][w][lane];
        breg += alpha * dot;
        // in-wave softmax over k=lane
        float m = breg;
        #pragma unroll
        for (int off = 32; off; off >>= 1) m = fmaxf(m, __shfl_xor(m, off));
        float e = expf(breg - m);
        float se = e;
        #pragma unroll
        for (int off = 32; off; off >>= 1) se += __shfl_xor(se, off);
        float dl = e / se;                      // d[k=lane]
        #pragma unroll
        for (int j = 0; j < 4; ++j) chv[j] = 0.f;
        #pragma unroll
        for (int i = 0; i < 4; ++i)
            #pragma unroll
            for (int r = 0; r < 4; ++r) {
                float dk = __shfl(dl, i * 16 + l4 * 4 + r);
                #pragma unroll
                for (int j = 0; j < 4; ++j)
                    chv[j] += dk * acc[i * 4 + j][r];
            }
        #pragma unroll
        for (int j = 0; j < 4; ++j) {
            chv[j] += __shfl_xor(chv[j], 16);
            chv[j] += __shfl_xor(chv[j], 32);
        }
        float p = chv[0] * chv[0] + chv[1] * chv[1] + chv[2] * chv[2] + chv[3] * chv[3];
        #pragma unroll
        for (int off = 1; off <= 8; off <<= 1) p += __shfl_xor(p, off);
        if (lane == 0) redp[wp][wave] = p;

        if (it < 2) {
            #pragma unroll
            for (int i = 0; i < 4; ++i)
                #pragma unroll
                for (int r = 0; r < 4; ++r) {
                    float s = acc[i * 4 + 0][r] * chv[0] + acc[i * 4 + 1][r] * chv[1]
                            + acc[i * 4 + 2][r] * chv[2] + acc[i * 4 + 3][r] * chv[3];
                    #pragma unroll
                    for (int off = 1; off <= 8; off <<= 1) s += __shfl_xor(s, off);
                    if (l15 == 0) bpart[wp][wave][i * 16 + l4 * 4 + r] = s;
                }
            __syncthreads();
        } else {
            if (l4 == 0) {
                #pragma unroll
                for (int j = 0; j < 4; ++j)
                    chatL[wave * 64 + j * 16 + l15] = chv[j];
            }
            __syncthreads();
            float n2f = 0.f;
            #pragma unroll
            for (int w = 0; w < 8; ++w) n2f += redp[wp][w];
            float alphaf = sqrtf(n2f) / (1.0f + n2f);
            out[(size_t)c * HD + tid] = alphaf * chatL[tid];
        }
    }
}

extern "C" void kernel_launch(void* const* d_in, const int* in_sizes, int n_in,
                              void* d_out, int out_size, void* d_ws, size_t ws_size,
                              hipStream_t stream) {
    const float* enc = (const float*)d_in[0];   // [1024, 64, 512] fp32
    const float* W   = (const float*)d_in[1];   // [512, 512] fp32
    float* out       = (float*)d_out;           // [1024, 512] fp32
    _Float16* Wp     = (_Float16*)d_ws;         // 512 KB, B-fragment order
    (void)in_sizes; (void)n_in; (void)ws_size; (void)out_size;

    cast_w_kernel<<<128, 256, 0, stream>>>(W, Wp);
    routing_kernel<<<1024, NT, 0, stream>>>(enc, Wp, out);
}